// Round 6
// baseline (269.613 us; speedup 1.0000x reference)
//
#include <hip/hip_runtime.h>

// x: (B=32, H=256, W=256, C=16) float32, row-major.
// p[h][w] = mean over (b, c) of x[b][h][w][c]  (512 values per (h,w))
// out = p >= 0.25 ? x*0.25/p : 1 - (0.75/(1-p))*(1-x)  ==  a*x + d
//
// Round 8: ALL-LINEAR 3-KERNEL PIPELINE. Evidence: six structural variants
// (fused/LDS/staged/split/8-load/16-load, NT and plain stores, occupancy
// 33-67%) ALL converge at ~2.4 TB/s HBM; the only fast kernels observed on
// this chip (harness fill 6.7 TB/s, m13 copy 6.3 TB/s) are strictly linear.
// Shared property of all slow variants: per-wave access split across 4-8
// regions at 4-32 MiB stride (forced by fusing the (b,c)-reduction with the
// apply) => ~20K concurrent scattered 1-KiB streams device-wide => DRAM
// row/channel thrash. Fix: no kernel ever strides.
//   A reduce_part: block = 64 KiB contiguous chunk of x; thread = 256 B.
//     Emits p_part[b][hw] c-sums (8 MB, coalesced f4 writes).
//   B finalize:    p_part summed over b (per-b rows coalesced) -> ad[hw]
//     (a,d) table, 512 KB.
//   C apply:       block = 64 KiB contiguous; thread = 256 B = 4 hw groups;
//     2 cached table loads per thread, 16 x {load f4, fma, store}.
// Traffic 420 MB all-linear (~70 us at fill rate) vs 268 MB strided
// (~87 us measured). Diagnostic: if C still runs ~3 TB/s despite perfect
// linearity, the stride theory dies and ~85 us was the machine's answer.

#define ALPHA 0.25f

typedef float v4f __attribute__((ext_vector_type(4)));

// ---------------- A: linear partial reduce (c-sums per (b,hw)) -------------
__global__ __launch_bounds__(256) void reduce_part_kernel(
    const float* __restrict__ x, float* __restrict__ p_part) {
  // Block chunk = 16384 floats (64 KiB) contiguous; thread = 64 floats.
  const long fbase = (long)blockIdx.x * 16384 + threadIdx.x * 64;
  const float4* __restrict__ xp = (const float4*)(x + fbase);

  float cs[4];
#pragma unroll
  for (int k = 0; k < 4; ++k) {          // 4 hw positions per thread
    float s = 0.0f;
#pragma unroll
    for (int j = 0; j < 4; ++j) {        // 16 c = 4 float4
      const float4 v = xp[4 * k + j];
      s += (v.x + v.y) + (v.z + v.w);
    }
    cs[k] = s;
  }
  // batch = blk/64 (64 KiB * 64 = 4 MiB per batch); hw coalesced f4 write.
  const int b  = blockIdx.x >> 6;
  const int hw = ((blockIdx.x & 63) << 10) + (threadIdx.x << 2);
  v4f o = {cs[0], cs[1], cs[2], cs[3]};
  *(v4f*)(p_part + (long)b * 65536 + hw) = o;
}

// ---------------- B: finalize p -> (a,d) table -----------------------------
__global__ __launch_bounds__(256) void finalize_kernel(
    const float* __restrict__ p_part, float2* __restrict__ ad) {
  const int hw = blockIdx.x * 256 + threadIdx.x;  // 0..65535
  float s = 0.0f;
#pragma unroll
  for (int b = 0; b < 32; ++b) {        // each b-row is a coalesced read
    s += p_part[(long)b * 65536 + hw];
  }
  const float p = s * (1.0f / 512.0f);
  float a, d;
  if (p >= ALPHA) {
    a = ALPHA / p;
    d = 0.0f;
  } else {
    const float beta = (1.0f - ALPHA) / (1.0f - p);
    a = beta;
    d = 1.0f - beta;
  }
  ad[hw] = make_float2(a, d);
}

// ---------------- C: linear apply out = a*x + d ----------------------------
__global__ __launch_bounds__(256) void apply_kernel(
    const float* __restrict__ x, const float2* __restrict__ ad,
    float* __restrict__ out) {
  const long g = (long)blockIdx.x * 256 + threadIdx.x;  // 0..524287
  const long f4base = g * 16;                 // 16 consecutive f4 = 256 B
  const int  inb = (int)f4base & ((1 << 18) - 1);  // in-batch f4 index
  const int  hw0 = inb >> 2;                  // 4 hw per thread

  float2 t[4];
#pragma unroll
  for (int k = 0; k < 4; ++k) t[k] = ad[hw0 + k];  // L2-cached table

  const float4* __restrict__ xp = (const float4*)x + f4base;
  v4f* __restrict__ op = (v4f*)out + f4base;
#pragma unroll
  for (int j = 0; j < 16; ++j) {
    const float4 v = xp[j];
    const float a = t[j >> 2].x;
    const float d = t[j >> 2].y;
    v4f r;
    r.x = fmaf(a, v.x, d);
    r.y = fmaf(a, v.y, d);
    r.z = fmaf(a, v.z, d);
    r.w = fmaf(a, v.w, d);
    op[j] = r;
  }
}

extern "C" void kernel_launch(void* const* d_in, const int* in_sizes, int n_in,
                              void* d_out, int out_size, void* d_ws, size_t ws_size,
                              hipStream_t stream) {
  const float* x = (const float*)d_in[0];
  float* out = (float*)d_out;
  float*  p_part = (float*)d_ws;                          // 8 MiB
  float2* ad     = (float2*)((char*)d_ws + 32L * 65536 * 4);  // +512 KiB

  reduce_part_kernel<<<dim3(2048), dim3(256), 0, stream>>>(x, p_part);
  finalize_kernel  <<<dim3(256),  dim3(256), 0, stream>>>(p_part, ad);
  apply_kernel     <<<dim3(2048), dim3(256), 0, stream>>>(x, ad, out);
}